// Round 4
// baseline (431.542 us; speedup 1.0000x reference)
//
#include <hip/hip_runtime.h>
#include <math.h>

#define D 128
#define OUTD 64
#define BM 128

static __device__ __forceinline__ float bf2f(unsigned short u) {
  return __uint_as_float(((unsigned int)u) << 16);
}
static __device__ __forceinline__ unsigned short f2bf(float f) {
  unsigned int u = __float_as_uint(f);
  u = (u + 0x7fff + ((u >> 16) & 1)) >> 16;   // RNE
  return (unsigned short)u;
}

// ---------------- CSR build ----------------

__global__ void k_hist(const int* __restrict__ ei, int* __restrict__ deg, int E) {
  int e = blockIdx.x * 256 + threadIdx.x;
  if (e < E) atomicAdd(&deg[ei[E + e]], 1);
}

// block-local exclusive scan of 1024 elems; partial[b] = block total
__global__ __launch_bounds__(1024) void k_scan1(const int* __restrict__ deg,
                                                int* __restrict__ offs,
                                                int* __restrict__ partial, int N) {
  __shared__ int wsum[16];
  int tid = threadIdx.x, lane = tid & 63, wv = tid >> 6;
  int i = blockIdx.x * 1024 + tid;
  int v = (i < N) ? deg[i] : 0;
  int x = v;
#pragma unroll
  for (int off = 1; off < 64; off <<= 1) {
    int t = __shfl_up(x, off);
    if (lane >= off) x += t;
  }
  if (lane == 63) wsum[wv] = x;
  __syncthreads();
  if (wv == 0) {
    int s = (lane < 16) ? wsum[lane] : 0;
#pragma unroll
    for (int off = 1; off < 16; off <<= 1) {
      int t = __shfl_up(s, off);
      if (lane >= off) s += t;
    }
    if (lane < 16) wsum[lane] = s;
  }
  __syncthreads();
  int wexcl = (wv == 0) ? 0 : wsum[wv - 1];
  if (i < N) offs[i] = wexcl + x - v;
  if (tid == 0) partial[blockIdx.x] = wsum[15];
}

// single-block exclusive scan (for partials, nb <= 1024)
__global__ __launch_bounds__(1024) void k_scan(const int* __restrict__ deg,
                                               int* __restrict__ offs, int N) {
  __shared__ int wsum[16];
  __shared__ int s_carry;
  int tid = threadIdx.x, lane = tid & 63, wv = tid >> 6;
  if (tid == 0) s_carry = 0;
  __syncthreads();
  for (int base = 0; base < N; base += 1024) {
    int i = base + tid;
    int v = (i < N) ? deg[i] : 0;
    int x = v;
#pragma unroll
    for (int off = 1; off < 64; off <<= 1) {
      int t = __shfl_up(x, off);
      if (lane >= off) x += t;
    }
    if (lane == 63) wsum[wv] = x;
    __syncthreads();
    if (wv == 0) {
      int s = (lane < 16) ? wsum[lane] : 0;
#pragma unroll
      for (int off = 1; off < 16; off <<= 1) {
        int t = __shfl_up(s, off);
        if (lane >= off) s += t;
      }
      if (lane < 16) wsum[lane] = s;
    }
    __syncthreads();
    int wexcl = (wv == 0) ? 0 : wsum[wv - 1];
    if (i < N) offs[i] = s_carry + wexcl + x - v;
    __syncthreads();
    if (tid == 1023) s_carry += wsum[15];
    __syncthreads();
  }
  if (tid == 0) offs[N] = s_carry;
}

__global__ __launch_bounds__(1024) void k_add(int* __restrict__ offs,
                                              const int* __restrict__ partialx, int N) {
  int i = blockIdx.x * 1024 + threadIdx.x;
  int a = partialx[blockIdx.x];
  if (i < N) offs[i] += a;
}

// atomicAdd directly on offs: afterwards offs[n] = END of node n's range.
__global__ void k_fill(const int* __restrict__ ei, int* __restrict__ offs,
                       int* __restrict__ csr_src, int E) {
  int e = blockIdx.x * 256 + threadIdx.x;
  if (e < E) {
    int d = ei[E + e];
    int pos = atomicAdd(&offs[d], 1);
    csr_src[pos] = ei[e];
  }
}

// ---------------- fold head weights: Wc = Wp1 @ Wp2, bc = bp1 @ Wp2 + bp2 ----------------

__global__ __launch_bounds__(256) void k_fold(const float* __restrict__ Wp1,
                                              const float* __restrict__ bp1,
                                              const float* __restrict__ Wp2,
                                              const float* __restrict__ bp2,
                                              float* __restrict__ Wc,
                                              float* __restrict__ bc) {
  int gid = blockIdx.x * 256 + threadIdx.x;   // 8192 threads
  int i = gid >> 6, j = gid & 63;
  float acc = 0.f;
  for (int k = 0; k < 128; ++k) acc += Wp1[i * 128 + k] * Wp2[k * 64 + j];
  Wc[i * 64 + j] = acc;
  if (gid < 64) {
    float b = bp2[gid];
    for (int k = 0; k < 128; ++k) b += bp1[k] * Wp2[k * 64 + gid];
    bc[gid] = b;
  }
}

// ---------------- GEMM + fused attention score projections ----------------
// H(bf16)[M x 128] = A @ W + bias; sdst = H.att[0:128]; ssrc = H.att[128:256]

__global__ __launch_bounds__(256) void k_gemm_gat(const float* __restrict__ A,
                                                  const float* __restrict__ W,
                                                  const float* __restrict__ bias,
                                                  const float* __restrict__ att,
                                                  unsigned short* __restrict__ H,
                                                  float* __restrict__ sdst,
                                                  float* __restrict__ ssrc, int M) {
  __shared__ float xs[32 * 132];   // [kk][row], pad 132
  __shared__ float ws[32 * 128];   // [kk][col]
  int tid = threadIdx.x;
  int row0 = blockIdx.x * BM;
  int cgrp = tid & 15;             // cols cgrp*8 .. +7
  int rgrp = tid >> 4;             // rows rgrp*8 .. +7

  float acc[8][8] = {};

  const float4* A4 = (const float4*)A;
  const float4* W4 = (const float4*)W;
  float4* ws4 = (float4*)ws;

  for (int kt = 0; kt < 4; ++kt) {
    __syncthreads();
#pragma unroll
    for (int i = 0; i < 4; ++i) {
      int idx = tid + 256 * i;
      int r = idx >> 3, c4 = idx & 7;
      int gr = row0 + r;
      float4 v = (gr < M) ? A4[(size_t)gr * 32 + kt * 8 + c4]
                          : make_float4(0.f, 0.f, 0.f, 0.f);
      int kb = c4 * 4;
      xs[(kb + 0) * 132 + r] = v.x;
      xs[(kb + 1) * 132 + r] = v.y;
      xs[(kb + 2) * 132 + r] = v.z;
      xs[(kb + 3) * 132 + r] = v.w;
    }
#pragma unroll
    for (int i = 0; i < 4; ++i) {
      int idx = tid + 256 * i;
      ws4[idx] = W4[kt * 1024 + idx];
    }
    __syncthreads();
#pragma unroll 8
    for (int kk = 0; kk < 32; ++kk) {
      float4 a0 = *(const float4*)&xs[kk * 132 + rgrp * 8];
      float4 a1 = *(const float4*)&xs[kk * 132 + rgrp * 8 + 4];
      float4 w0 = *(const float4*)&ws[kk * 128 + cgrp * 8];
      float4 w1 = *(const float4*)&ws[kk * 128 + cgrp * 8 + 4];
      float a[8] = {a0.x, a0.y, a0.z, a0.w, a1.x, a1.y, a1.z, a1.w};
      float w[8] = {w0.x, w0.y, w0.z, w0.w, w1.x, w1.y, w1.z, w1.w};
#pragma unroll
      for (int r = 0; r < 8; ++r)
#pragma unroll
        for (int c = 0; c < 8; ++c) acc[r][c] += a[r] * w[c];
    }
  }

  float4 b0 = *(const float4*)&bias[cgrp * 8];
  float4 b1 = *(const float4*)&bias[cgrp * 8 + 4];
  float bb[8] = {b0.x, b0.y, b0.z, b0.w, b1.x, b1.y, b1.z, b1.w};
#pragma unroll
  for (int r = 0; r < 8; ++r)
#pragma unroll
    for (int c = 0; c < 8; ++c) acc[r][c] += bb[c];

  // store H as bf16 (row = 128 bf16 = 32 ushort4)
  ushort4* H4 = (ushort4*)H;
#pragma unroll
  for (int r = 0; r < 8; ++r) {
    int gr = row0 + rgrp * 8 + r;
    if (gr < M) {
      ushort4 p0, p1;
      p0.x = f2bf(acc[r][0]); p0.y = f2bf(acc[r][1]);
      p0.z = f2bf(acc[r][2]); p0.w = f2bf(acc[r][3]);
      p1.x = f2bf(acc[r][4]); p1.y = f2bf(acc[r][5]);
      p1.z = f2bf(acc[r][6]); p1.w = f2bf(acc[r][7]);
      H4[(size_t)gr * 32 + cgrp * 2] = p0;
      H4[(size_t)gr * 32 + cgrp * 2 + 1] = p1;
    }
  }

  // fused score projections (fp32, from the fp32 accumulators)
  float4 ai0 = *(const float4*)&att[cgrp * 8];
  float4 ai1 = *(const float4*)&att[cgrp * 8 + 4];
  float4 aj0 = *(const float4*)&att[128 + cgrp * 8];
  float4 aj1 = *(const float4*)&att[128 + cgrp * 8 + 4];
  float ai[8] = {ai0.x, ai0.y, ai0.z, ai0.w, ai1.x, ai1.y, ai1.z, ai1.w};
  float aj[8] = {aj0.x, aj0.y, aj0.z, aj0.w, aj1.x, aj1.y, aj1.z, aj1.w};
#pragma unroll
  for (int r = 0; r < 8; ++r) {
    float pi = 0.f, pj = 0.f;
#pragma unroll
    for (int c = 0; c < 8; ++c) {
      pi += acc[r][c] * ai[c];
      pj += acc[r][c] * aj[c];
    }
#pragma unroll
    for (int off = 1; off < 16; off <<= 1) {
      pi += __shfl_xor(pi, off);
      pj += __shfl_xor(pj, off);
    }
    if (cgrp == 0) {
      int gr = row0 + rgrp * 8 + r;
      if (gr < M) {
        sdst[gr] = pi;
        ssrc[gr] = pj;
      }
    }
  }
}

// ---------------- softmax + aggregation: 2 nodes per wave, online softmax ----------------
// offs holds END offsets (start of node n = offs[n-1], or 0).

__global__ __launch_bounds__(256) void k_gather(const ushort4* __restrict__ H4,
                                                const float* __restrict__ sdst,
                                                const float* __restrict__ ssrc,
                                                const int* __restrict__ csr,
                                                const int* __restrict__ offs,
                                                const float* __restrict__ bias,
                                                float* __restrict__ xout, int N) {
  int tid = threadIdx.x;
  int wv = tid >> 6, lane = tid & 63, sub = lane >> 5, l32 = lane & 31;
  int n = blockIdx.x * 8 + wv * 2 + sub;
  bool valid = (n < N);
  int end = valid ? offs[n] : 0;
  int start = (valid && n > 0) ? offs[n - 1] : 0;
  float sdn = valid ? sdst[n] : 0.f;

  float m = -INFINITY, ssum = 0.f;
  float4 acc = make_float4(0.f, 0.f, 0.f, 0.f);

  for (int base = start; base < end; base += 32) {
    int k = base + l32;
    int s = 0;
    float sc = -INFINITY;
    if (k < end) {
      s = csr[k];
      float e = sdn + ssrc[s];
      sc = e > 0.f ? e : 0.2f * e;
    }
    float cm = sc;
#pragma unroll
    for (int off = 16; off; off >>= 1) cm = fmaxf(cm, __shfl_xor(cm, off));
    float nm = fmaxf(m, cm);
    float scale = __expf(m - nm);          // first chunk: exp(-inf)=0, acc/ssum are 0
    acc.x *= scale; acc.y *= scale; acc.z *= scale; acc.w *= scale;
    float w = (k < end) ? __expf(sc - nm) : 0.f;
    float cs = w;
#pragma unroll
    for (int off = 16; off; off >>= 1) cs += __shfl_xor(cs, off);
    ssum = ssum * scale + cs;
    m = nm;
    int cc = end - base; if (cc > 32) cc = 32;
    for (int j = 0; j < cc; ++j) {
      float wj = __shfl(w, sub * 32 + j);
      int sj = __shfl(s, sub * 32 + j);
      ushort4 hv = H4[(size_t)sj * 32 + l32];
      acc.x += wj * bf2f(hv.x);
      acc.y += wj * bf2f(hv.y);
      acc.z += wj * bf2f(hv.z);
      acc.w += wj * bf2f(hv.w);
    }
  }

  if (valid) {
    float inv = 1.0f / (ssum + 1e-16f);
    float4 b = ((const float4*)bias)[l32];
    float4 o;
    o.x = fmaxf(acc.x * inv + b.x, 0.f);
    o.y = fmaxf(acc.y * inv + b.y, 0.f);
    o.z = fmaxf(acc.z * inv + b.z, 0.f);
    o.w = fmaxf(acc.w * inv + b.w, 0.f);
    ((float4*)xout)[(size_t)n * 32 + l32] = o;
  }
}

// ---------------- head: out = log_softmax(x @ Wc + bc) ----------------
// 64 nodes per 256-thread block; thread (node = tid&63, jg = tid>>6) computes
// 16 of the node's 64 logits. jg is wave-uniform -> Wc reads are s_loads.

__global__ __launch_bounds__(256) void k_head3(const float* __restrict__ X,
                                               const float* __restrict__ Wc,
                                               const float* __restrict__ bc,
                                               float* __restrict__ out, int N) {
  __shared__ float xs[64 * 132];       // row stride 132: b128-aligned, 2-way banks on read
  __shared__ float rmax[4][64];
  __shared__ float rsum[4][64];
  int tid = threadIdx.x;
  int row0 = blockIdx.x * 64;

  const float4* X4 = (const float4*)X;
#pragma unroll
  for (int i = 0; i < 8; ++i) {
    int idx = tid + 256 * i;           // 0..2047
    int r = idx >> 5, c4 = idx & 31;
    int gr = row0 + r;
    float4 v = (gr < N) ? X4[(size_t)gr * 32 + c4] : make_float4(0.f, 0.f, 0.f, 0.f);
    *(float4*)&xs[r * 132 + c4 * 4] = v;
  }
  __syncthreads();

  int node = tid & 63, jg = tid >> 6;  // jg wave-uniform
  const float* xrow = xs + node * 132;
  const float* Wg = Wc + jg * 16;

  float acc[16] = {};
  for (int k4 = 0; k4 < 32; ++k4) {
    float4 a = *(const float4*)&xrow[k4 * 4];
    const float* w0 = Wg + (k4 * 4) * 64;     // wave-uniform -> s_load
#pragma unroll
    for (int j = 0; j < 16; ++j) {
      acc[j] = fmaf(a.x, w0[j], acc[j]);
      acc[j] = fmaf(a.y, w0[64 + j], acc[j]);
      acc[j] = fmaf(a.z, w0[128 + j], acc[j]);
      acc[j] = fmaf(a.w, w0[192 + j], acc[j]);
    }
  }

#pragma unroll
  for (int j = 0; j < 16; ++j) acc[j] += bc[jg * 16 + j];

  float mx = -INFINITY;
#pragma unroll
  for (int j = 0; j < 16; ++j) mx = fmaxf(mx, acc[j]);
  rmax[jg][node] = mx;
  __syncthreads();
  float m = fmaxf(fmaxf(rmax[0][node], rmax[1][node]),
                  fmaxf(rmax[2][node], rmax[3][node]));
  float s = 0.f;
#pragma unroll
  for (int j = 0; j < 16; ++j) s += __expf(acc[j] - m);
  rsum[jg][node] = s;
  __syncthreads();
  float tot = rsum[0][node] + rsum[1][node] + rsum[2][node] + rsum[3][node];
  float ls = m + __logf(tot);

  int n = row0 + node;
  if (n < N) {
    float4* o4 = (float4*)(out + (size_t)n * 64 + jg * 16);
#pragma unroll
    for (int q = 0; q < 4; ++q)
      o4[q] = make_float4(acc[q * 4] - ls, acc[q * 4 + 1] - ls,
                          acc[q * 4 + 2] - ls, acc[q * 4 + 3] - ls);
  }
}

// ---------------- launch ----------------

extern "C" void kernel_launch(void* const* d_in, const int* in_sizes, int n_in,
                              void* d_out, int out_size, void* d_ws, size_t ws_size,
                              hipStream_t stream) {
  const float* x      = (const float*)d_in[0];
  const int*   ei     = (const int*)d_in[1];
  const float* Ws     = (const float*)d_in[2];
  const float* bs     = (const float*)d_in[3];
  const float* atts   = (const float*)d_in[4];
  const float* biases = (const float*)d_in[5];
  const float* Wp1    = (const float*)d_in[6];
  const float* bp1    = (const float*)d_in[7];
  const float* Wp2    = (const float*)d_in[8];
  const float* bp2    = (const float*)d_in[9];
  float* out = (float*)d_out;

  int N = in_sizes[0] / 128;
  int E = in_sizes[1] / 2;
  int Np = (N + 3) & ~3;
  int nb = (N + 1023) / 1024;

  float* xbuf = (float*)d_ws;                       // N*128 f32
  unsigned short* H = (unsigned short*)(xbuf + (size_t)N * 128);  // N*128 bf16
  float* sdst = (float*)(H + (size_t)Np * 128);
  float* ssrc = sdst + Np;
  float* Wc   = ssrc + Np;
  float* bc   = Wc + 128 * 64;
  int* deg    = (int*)(bc + 64);
  int* offs   = deg + Np;
  int* partial  = offs + Np;
  int* partialx = partial + 1024;
  int* csr      = partialx + 1028;

  // fold head weights
  k_fold<<<32, 256, 0, stream>>>(Wp1, bp1, Wp2, bp2, Wc, bc);

  // CSR by dst
  hipMemsetAsync(deg, 0, (size_t)N * sizeof(int), stream);
  k_hist<<<(E + 255) / 256, 256, 0, stream>>>(ei, deg, E);
  k_scan1<<<nb, 1024, 0, stream>>>(deg, offs, partial, N);
  k_scan<<<1, 1024, 0, stream>>>(partial, partialx, nb);
  k_add<<<nb, 1024, 0, stream>>>(offs, partialx, N);
  k_fill<<<(E + 255) / 256, 256, 0, stream>>>(ei, offs, csr, E);   // offs -> ends

  const float* xin = x;
  for (int l = 0; l < 3; ++l) {
    k_gemm_gat<<<(N + BM - 1) / BM, 256, 0, stream>>>(
        xin, Ws + (size_t)l * 128 * 128, bs + (size_t)l * 128,
        atts + (size_t)l * 256, H, sdst, ssrc, N);
    k_gather<<<(N + 7) / 8, 256, 0, stream>>>((const ushort4*)H, sdst, ssrc, csr, offs,
                                              biases + (size_t)l * 128, xbuf, N);
    xin = xbuf;
  }

  k_head3<<<(N + 63) / 64, 256, 0, stream>>>(xbuf, Wc, bc, out, N);
}

// Round 5
// 337.555 us; speedup vs baseline: 1.2784x; 1.2784x over previous
//
#include <hip/hip_runtime.h>
#include <math.h>

#define D 128
#define OUTD 64

typedef __attribute__((ext_vector_type(8))) short short8;
typedef __attribute__((ext_vector_type(4))) float floatx4;

static __device__ __forceinline__ float bf2f(unsigned short u) {
  return __uint_as_float(((unsigned int)u) << 16);
}
static __device__ __forceinline__ unsigned short f2bf(float f) {
  unsigned int u = __float_as_uint(f);
  u = (u + 0x7fff + ((u >> 16) & 1)) >> 16;   // RNE
  return (unsigned short)u;
}

// ---------------- CSR build ----------------

__global__ void k_hist(const int* __restrict__ ei, int* __restrict__ deg, int E) {
  int e = blockIdx.x * 256 + threadIdx.x;
  if (e < E) atomicAdd(&deg[ei[E + e]], 1);
}

__global__ __launch_bounds__(1024) void k_scan1(const int* __restrict__ deg,
                                                int* __restrict__ offs,
                                                int* __restrict__ partial, int N) {
  __shared__ int wsum[16];
  int tid = threadIdx.x, lane = tid & 63, wv = tid >> 6;
  int i = blockIdx.x * 1024 + tid;
  int v = (i < N) ? deg[i] : 0;
  int x = v;
#pragma unroll
  for (int off = 1; off < 64; off <<= 1) {
    int t = __shfl_up(x, off);
    if (lane >= off) x += t;
  }
  if (lane == 63) wsum[wv] = x;
  __syncthreads();
  if (wv == 0) {
    int s = (lane < 16) ? wsum[lane] : 0;
#pragma unroll
    for (int off = 1; off < 16; off <<= 1) {
      int t = __shfl_up(s, off);
      if (lane >= off) s += t;
    }
    if (lane < 16) wsum[lane] = s;
  }
  __syncthreads();
  int wexcl = (wv == 0) ? 0 : wsum[wv - 1];
  if (i < N) offs[i] = wexcl + x - v;
  if (tid == 0) partial[blockIdx.x] = wsum[15];
}

__global__ __launch_bounds__(1024) void k_scan(const int* __restrict__ deg,
                                               int* __restrict__ offs, int N) {
  __shared__ int wsum[16];
  __shared__ int s_carry;
  int tid = threadIdx.x, lane = tid & 63, wv = tid >> 6;
  if (tid == 0) s_carry = 0;
  __syncthreads();
  for (int base = 0; base < N; base += 1024) {
    int i = base + tid;
    int v = (i < N) ? deg[i] : 0;
    int x = v;
#pragma unroll
    for (int off = 1; off < 64; off <<= 1) {
      int t = __shfl_up(x, off);
      if (lane >= off) x += t;
    }
    if (lane == 63) wsum[wv] = x;
    __syncthreads();
    if (wv == 0) {
      int s = (lane < 16) ? wsum[lane] : 0;
#pragma unroll
      for (int off = 1; off < 16; off <<= 1) {
        int t = __shfl_up(s, off);
        if (lane >= off) s += t;
      }
      if (lane < 16) wsum[lane] = s;
    }
    __syncthreads();
    int wexcl = (wv == 0) ? 0 : wsum[wv - 1];
    if (i < N) offs[i] = s_carry + wexcl + x - v;
    __syncthreads();
    if (tid == 1023) s_carry += wsum[15];
    __syncthreads();
  }
  if (tid == 0) offs[N] = s_carry;
}

__global__ __launch_bounds__(1024) void k_add(int* __restrict__ offs,
                                              const int* __restrict__ partialx, int N) {
  int i = blockIdx.x * 1024 + threadIdx.x;
  int a = partialx[blockIdx.x];
  if (i < N) offs[i] += a;
}

// atomicAdd directly on offs: afterwards offs[n] = END of node n's range.
__global__ void k_fill(const int* __restrict__ ei, int* __restrict__ offs,
                       int* __restrict__ csr_src, int E) {
  int e = blockIdx.x * 256 + threadIdx.x;
  if (e < E) {
    int d = ei[E + e];
    int pos = atomicAdd(&offs[d], 1);
    csr_src[pos] = ei[e];
  }
}

// ---------------- weight prep ----------------
// Wt[l][n][k] = Ws[l][k][n]  (bf16)

__global__ __launch_bounds__(256) void k_prep(const float* __restrict__ Ws,
                                              unsigned short* __restrict__ Wt) {
  int gid = blockIdx.x * 256 + threadIdx.x;     // 49152
  int l = gid >> 14;
  int rem = gid & 16383;
  int k = rem >> 7, n = rem & 127;
  Wt[l * 16384 + n * 128 + k] = f2bf(Ws[gid]);
}

// Wct[j][k] = (Wp1 @ Wp2)[k][j] (bf16), bc = bp1 @ Wp2 + bp2 (f32)
__global__ __launch_bounds__(256) void k_fold(const float* __restrict__ Wp1,
                                              const float* __restrict__ bp1,
                                              const float* __restrict__ Wp2,
                                              const float* __restrict__ bp2,
                                              unsigned short* __restrict__ Wct,
                                              float* __restrict__ bc) {
  int gid = blockIdx.x * 256 + threadIdx.x;   // 8192
  int i = gid >> 6, j = gid & 63;             // i = k, j = out col
  float acc = 0.f;
  for (int k = 0; k < 128; ++k) acc += Wp1[i * 128 + k] * Wp2[k * 64 + j];
  Wct[j * 128 + i] = f2bf(acc);
  if (gid < 64) {
    float b = bp2[gid];
    for (int k = 0; k < 128; ++k) b += bp1[k] * Wp2[k * 64 + gid];
    bc[gid] = b;
  }
}

// f32 -> bf16 vector convert (n4 = count/4)
__global__ void k_cvt(const float4* __restrict__ src, ushort4* __restrict__ dst, int n4) {
  int i = blockIdx.x * 256 + threadIdx.x;
  if (i < n4) {
    float4 v = src[i];
    ushort4 p;
    p.x = f2bf(v.x); p.y = f2bf(v.y); p.z = f2bf(v.z); p.w = f2bf(v.w);
    dst[i] = p;
  }
}

// ---------------- MFMA GEMM + fused attention scores ----------------
// H(bf16)[M x 128] = bf16(A) @ bf16(W) + bias ; sdst/ssrc from f32 accumulators.
// 128-row tile, 4 waves in 2x2 (64 rows x 64 cols each), frags from global.
// A frag: lane holds A[m = lane&15][k = (lane>>4)*8 + j]; B frag same with n.
// C/D: col = lane&15, row = (lane>>4)*4 + reg.

__global__ __launch_bounds__(256) void k_gemm_mfma(const unsigned short* __restrict__ Ab,
                                                   const unsigned short* __restrict__ Bt,
                                                   const float* __restrict__ bias,
                                                   const float* __restrict__ att,
                                                   unsigned short* __restrict__ H,
                                                   float* __restrict__ sdst,
                                                   float* __restrict__ ssrc, int M) {
  __shared__ float spi[2][128];
  __shared__ float spj[2][128];
  int tid = threadIdx.x;
  int w = tid >> 6, l = tid & 63;
  int g = l >> 4, li = l & 15;
  int row0 = blockIdx.x * 128;
  int mw = (w >> 1) * 64, nw = (w & 1) * 64;

  floatx4 acc[4][4] = {};

  for (int ks = 0; ks < 4; ++ks) {
    short8 fa[4], fb[4];
#pragma unroll
    for (int t = 0; t < 4; ++t) {
      int row = row0 + mw + t * 16 + li;
      row = row < M ? row : M - 1;
      fa[t] = *(const short8*)(Ab + (size_t)row * 128 + ks * 32 + g * 8);
      int n = nw + t * 16 + li;
      fb[t] = *(const short8*)(Bt + n * 128 + ks * 32 + g * 8);
    }
#pragma unroll
    for (int ti = 0; ti < 4; ++ti)
#pragma unroll
      for (int tj = 0; tj < 4; ++tj)
        acc[ti][tj] = __builtin_amdgcn_mfma_f32_16x16x32_bf16(fa[ti], fb[tj],
                                                              acc[ti][tj], 0, 0, 0);
  }

  float bb[4], ai4[4], aj4[4];
#pragma unroll
  for (int tj = 0; tj < 4; ++tj) {
    int col = nw + tj * 16 + li;
    bb[tj] = bias[col];
    ai4[tj] = att[col];
    aj4[tj] = att[128 + col];
  }

#pragma unroll
  for (int ti = 0; ti < 4; ++ti) {
    float pi[4] = {0.f, 0.f, 0.f, 0.f};
    float pj[4] = {0.f, 0.f, 0.f, 0.f};
#pragma unroll
    for (int tj = 0; tj < 4; ++tj) {
#pragma unroll
      for (int r = 0; r < 4; ++r) {
        float v = acc[ti][tj][r] + bb[tj];
        int row = row0 + mw + ti * 16 + g * 4 + r;
        if (row < M) H[(size_t)row * 128 + nw + tj * 16 + li] = f2bf(v);
        pi[r] += v * ai4[tj];
        pj[r] += v * aj4[tj];
      }
    }
#pragma unroll
    for (int r = 0; r < 4; ++r) {
#pragma unroll
      for (int off = 1; off < 16; off <<= 1) {
        pi[r] += __shfl_xor(pi[r], off);
        pj[r] += __shfl_xor(pj[r], off);
      }
      if (li == 0) {
        int rl = mw + ti * 16 + g * 4 + r;
        spi[w & 1][rl] = pi[r];
        spj[w & 1][rl] = pj[r];
      }
    }
  }
  __syncthreads();
  if (tid < 128) {
    int row = row0 + tid;
    if (row < M) {
      sdst[row] = spi[0][tid] + spi[1][tid];
      ssrc[row] = spj[0][tid] + spj[1][tid];
    }
  }
}

// ---------------- softmax + aggregation: 2 nodes per wave, online softmax ----------------
// offs holds END offsets (start of node n = offs[n-1], or 0). Output bf16.

__global__ __launch_bounds__(256) void k_gather(const ushort4* __restrict__ H4,
                                                const float* __restrict__ sdst,
                                                const float* __restrict__ ssrc,
                                                const int* __restrict__ csr,
                                                const int* __restrict__ offs,
                                                const float* __restrict__ bias,
                                                unsigned short* __restrict__ xout, int N) {
  int tid = threadIdx.x;
  int wv = tid >> 6, lane = tid & 63, sub = lane >> 5, l32 = lane & 31;
  int n = blockIdx.x * 8 + wv * 2 + sub;
  bool valid = (n < N);
  int end = valid ? offs[n] : 0;
  int start = (valid && n > 0) ? offs[n - 1] : 0;
  float sdn = valid ? sdst[n] : 0.f;

  float m = -INFINITY, ssum = 0.f;
  float4 acc = make_float4(0.f, 0.f, 0.f, 0.f);

  for (int base = start; base < end; base += 32) {
    int k = base + l32;
    int s = 0;
    float sc = -INFINITY;
    if (k < end) {
      s = csr[k];
      float e = sdn + ssrc[s];
      sc = e > 0.f ? e : 0.2f * e;
    }
    float cm = sc;
#pragma unroll
    for (int off = 16; off; off >>= 1) cm = fmaxf(cm, __shfl_xor(cm, off));
    float nm = fmaxf(m, cm);
    float scale = __expf(m - nm);
    acc.x *= scale; acc.y *= scale; acc.z *= scale; acc.w *= scale;
    float w = (k < end) ? __expf(sc - nm) : 0.f;
    float cs = w;
#pragma unroll
    for (int off = 16; off; off >>= 1) cs += __shfl_xor(cs, off);
    ssum = ssum * scale + cs;
    m = nm;
    int cc = end - base; if (cc > 32) cc = 32;
    for (int j = 0; j < cc; ++j) {
      float wj = __shfl(w, sub * 32 + j);
      int sj = __shfl(s, sub * 32 + j);
      ushort4 hv = H4[(size_t)sj * 32 + l32];
      acc.x += wj * bf2f(hv.x);
      acc.y += wj * bf2f(hv.y);
      acc.z += wj * bf2f(hv.z);
      acc.w += wj * bf2f(hv.w);
    }
  }

  if (valid) {
    float inv = 1.0f / (ssum + 1e-16f);
    float4 b = ((const float4*)bias)[l32];
    ushort4 o;
    o.x = f2bf(fmaxf(acc.x * inv + b.x, 0.f));
    o.y = f2bf(fmaxf(acc.y * inv + b.y, 0.f));
    o.z = f2bf(fmaxf(acc.z * inv + b.z, 0.f));
    o.w = f2bf(fmaxf(acc.w * inv + b.w, 0.f));
    ((ushort4*)xout)[(size_t)n * 32 + l32] = o;
  }
}

// ---------------- head: out = log_softmax(xb @ Wc + bc), MFMA ----------------
// 128-row tile, 4 waves, each 32 rows x 64 cols. log_softmax fused in C-layout.

__global__ __launch_bounds__(256) void k_head_mfma(const unsigned short* __restrict__ Xb,
                                                   const unsigned short* __restrict__ Wct,
                                                   const float* __restrict__ bc,
                                                   float* __restrict__ out, int M) {
  int tid = threadIdx.x;
  int w = tid >> 6, l = tid & 63;
  int g = l >> 4, li = l & 15;
  int row0 = blockIdx.x * 128;
  int mw = w * 32;

  floatx4 acc[2][4] = {};

  for (int ks = 0; ks < 4; ++ks) {
    short8 fa[2], fb[4];
#pragma unroll
    for (int t = 0; t < 2; ++t) {
      int row = row0 + mw + t * 16 + li;
      row = row < M ? row : M - 1;
      fa[t] = *(const short8*)(Xb + (size_t)row * 128 + ks * 32 + g * 8);
    }
#pragma unroll
    for (int t = 0; t < 4; ++t)
      fb[t] = *(const short8*)(Wct + (t * 16 + li) * 128 + ks * 32 + g * 8);
#pragma unroll
    for (int ti = 0; ti < 2; ++ti)
#pragma unroll
      for (int tj = 0; tj < 4; ++tj)
        acc[ti][tj] = __builtin_amdgcn_mfma_f32_16x16x32_bf16(fa[ti], fb[tj],
                                                              acc[ti][tj], 0, 0, 0);
  }

  float bb[4];
#pragma unroll
  for (int tj = 0; tj < 4; ++tj) bb[tj] = bc[tj * 16 + li];

#pragma unroll
  for (int ti = 0; ti < 2; ++ti) {
#pragma unroll
    for (int r = 0; r < 4; ++r) {
      float v[4];
      float mx = -INFINITY;
#pragma unroll
      for (int tj = 0; tj < 4; ++tj) {
        v[tj] = acc[ti][tj][r] + bb[tj];
        mx = fmaxf(mx, v[tj]);
      }
#pragma unroll
      for (int off = 1; off < 16; off <<= 1) mx = fmaxf(mx, __shfl_xor(mx, off));
      float s = 0.f;
#pragma unroll
      for (int tj = 0; tj < 4; ++tj) s += __expf(v[tj] - mx);
#pragma unroll
      for (int off = 1; off < 16; off <<= 1) s += __shfl_xor(s, off);
      float ls = mx + __logf(s);
      int row = row0 + mw + ti * 16 + g * 4 + r;
      if (row < M) {
#pragma unroll
        for (int tj = 0; tj < 4; ++tj)
          out[(size_t)row * 64 + tj * 16 + li] = v[tj] - ls;
      }
    }
  }
}

// ---------------- launch ----------------

extern "C" void kernel_launch(void* const* d_in, const int* in_sizes, int n_in,
                              void* d_out, int out_size, void* d_ws, size_t ws_size,
                              hipStream_t stream) {
  const float* x      = (const float*)d_in[0];
  const int*   ei     = (const int*)d_in[1];
  const float* Ws     = (const float*)d_in[2];
  const float* bs     = (const float*)d_in[3];
  const float* atts   = (const float*)d_in[4];
  const float* biases = (const float*)d_in[5];
  const float* Wp1    = (const float*)d_in[6];
  const float* bp1    = (const float*)d_in[7];
  const float* Wp2    = (const float*)d_in[8];
  const float* bp2    = (const float*)d_in[9];
  float* out = (float*)d_out;

  int N = in_sizes[0] / 128;
  int E = in_sizes[1] / 2;
  int Np = (N + 3) & ~3;
  int nb = (N + 1023) / 1024;

  float* sdst = (float*)d_ws;
  float* ssrc = sdst + Np;
  float* bc   = ssrc + Np;
  unsigned short* xb   = (unsigned short*)(bc + 64);   // bf16 layer-0 input
  unsigned short* xbuf = xb + (size_t)Np * 128;        // bf16 gather output
  unsigned short* H    = xbuf + (size_t)Np * 128;      // bf16 h
  unsigned short* Wt   = H + (size_t)Np * 128;         // 3 x [n][k]
  unsigned short* Wct  = Wt + 3 * 16384;               // [64][128]
  int* deg    = (int*)(Wct + 8192);
  int* offs   = deg + Np;
  int* partial  = offs + Np;
  int* partialx = partial + 1024;
  int* csr      = partialx + 1028;

  // weight prep + input convert (independent of CSR)
  k_prep<<<192, 256, 0, stream>>>(Ws, Wt);
  k_fold<<<32, 256, 0, stream>>>(Wp1, bp1, Wp2, bp2, Wct, bc);
  k_cvt<<<(N * 32 + 255) / 256, 256, 0, stream>>>((const float4*)x, (ushort4*)xb, N * 32);

  // CSR by dst
  hipMemsetAsync(deg, 0, (size_t)N * sizeof(int), stream);
  k_hist<<<(E + 255) / 256, 256, 0, stream>>>(ei, deg, E);
  k_scan1<<<nb, 1024, 0, stream>>>(deg, offs, partial, N);
  k_scan<<<1, 1024, 0, stream>>>(partial, partialx, nb);
  k_add<<<nb, 1024, 0, stream>>>(offs, partialx, N);
  k_fill<<<(E + 255) / 256, 256, 0, stream>>>(ei, offs, csr, E);   // offs -> ends

  const unsigned short* xin = xb;
  for (int l = 0; l < 3; ++l) {
    k_gemm_mfma<<<(N + 127) / 128, 256, 0, stream>>>(
        xin, Wt + (size_t)l * 16384, bs + (size_t)l * 128,
        atts + (size_t)l * 256, H, sdst, ssrc, N);
    k_gather<<<(N + 7) / 8, 256, 0, stream>>>((const ushort4*)H, sdst, ssrc, csr, offs,
                                              biases + (size_t)l * 128, xbuf, N);
    xin = xbuf;
  }

  k_head_mfma<<<(N + 127) / 128, 256, 0, stream>>>(xbuf, Wct, bc, out, N);
}

// Round 6
// 322.022 us; speedup vs baseline: 1.3401x; 1.0482x over previous
//
#include <hip/hip_runtime.h>
#include <math.h>

#define D 128
#define OUTD 64

typedef __attribute__((ext_vector_type(8))) short short8;
typedef __attribute__((ext_vector_type(4))) float floatx4;

static __device__ __forceinline__ float bf2f(unsigned short u) {
  return __uint_as_float(((unsigned int)u) << 16);
}
static __device__ __forceinline__ unsigned short f2bf(float f) {
  unsigned int u = __float_as_uint(f);
  u = (u + 0x7fff + ((u >> 16) & 1)) >> 16;   // RNE
  return (unsigned short)u;
}

// ---------------- CSR build ----------------

__global__ void k_hist(const int* __restrict__ ei, int* __restrict__ deg, int E) {
  int e = blockIdx.x * 256 + threadIdx.x;
  if (e < E) atomicAdd(&deg[ei[E + e]], 1);
}

__global__ __launch_bounds__(1024) void k_scan1(const int* __restrict__ deg,
                                                int* __restrict__ offs,
                                                int* __restrict__ partial, int N) {
  __shared__ int wsum[16];
  int tid = threadIdx.x, lane = tid & 63, wv = tid >> 6;
  int i = blockIdx.x * 1024 + tid;
  int v = (i < N) ? deg[i] : 0;
  int x = v;
#pragma unroll
  for (int off = 1; off < 64; off <<= 1) {
    int t = __shfl_up(x, off);
    if (lane >= off) x += t;
  }
  if (lane == 63) wsum[wv] = x;
  __syncthreads();
  if (wv == 0) {
    int s = (lane < 16) ? wsum[lane] : 0;
#pragma unroll
    for (int off = 1; off < 16; off <<= 1) {
      int t = __shfl_up(s, off);
      if (lane >= off) s += t;
    }
    if (lane < 16) wsum[lane] = s;
  }
  __syncthreads();
  int wexcl = (wv == 0) ? 0 : wsum[wv - 1];
  if (i < N) offs[i] = wexcl + x - v;
  if (tid == 0) partial[blockIdx.x] = wsum[15];
}

__global__ __launch_bounds__(1024) void k_scan(const int* __restrict__ deg,
                                               int* __restrict__ offs, int N) {
  __shared__ int wsum[16];
  __shared__ int s_carry;
  int tid = threadIdx.x, lane = tid & 63, wv = tid >> 6;
  if (tid == 0) s_carry = 0;
  __syncthreads();
  for (int base = 0; base < N; base += 1024) {
    int i = base + tid;
    int v = (i < N) ? deg[i] : 0;
    int x = v;
#pragma unroll
    for (int off = 1; off < 64; off <<= 1) {
      int t = __shfl_up(x, off);
      if (lane >= off) x += t;
    }
    if (lane == 63) wsum[wv] = x;
    __syncthreads();
    if (wv == 0) {
      int s = (lane < 16) ? wsum[lane] : 0;
#pragma unroll
      for (int off = 1; off < 16; off <<= 1) {
        int t = __shfl_up(s, off);
        if (lane >= off) s += t;
      }
      if (lane < 16) wsum[lane] = s;
    }
    __syncthreads();
    int wexcl = (wv == 0) ? 0 : wsum[wv - 1];
    if (i < N) offs[i] = s_carry + wexcl + x - v;
    __syncthreads();
    if (tid == 1023) s_carry += wsum[15];
    __syncthreads();
  }
  if (tid == 0) offs[N] = s_carry;
}

__global__ __launch_bounds__(1024) void k_add(int* __restrict__ offs,
                                              const int* __restrict__ partialx, int N) {
  int i = blockIdx.x * 1024 + threadIdx.x;
  int a = partialx[blockIdx.x];
  if (i < N) offs[i] += a;
}

// atomicAdd directly on offs: afterwards offs[n] = END of node n's range.
__global__ void k_fill(const int* __restrict__ ei, int* __restrict__ offs,
                       int* __restrict__ csr_src, int E) {
  int e = blockIdx.x * 256 + threadIdx.x;
  if (e < E) {
    int d = ei[E + e];
    int pos = atomicAdd(&offs[d], 1);
    csr_src[pos] = ei[e];
  }
}

// ---------------- weight prep (merged) ----------------
// blocks 0..191:  Wt[l][n][k] = Ws[l][k][n] (bf16)
// blocks 192..223: Wct[j][k] = (Wp1 @ Wp2)[k][j] (bf16), bc = bp1 @ Wp2 + bp2

__global__ __launch_bounds__(256) void k_prepfold(const float* __restrict__ Ws,
                                                  const float* __restrict__ Wp1,
                                                  const float* __restrict__ bp1,
                                                  const float* __restrict__ Wp2,
                                                  const float* __restrict__ bp2,
                                                  unsigned short* __restrict__ Wt,
                                                  unsigned short* __restrict__ Wct,
                                                  float* __restrict__ bc) {
  if (blockIdx.x < 192) {
    int gid = blockIdx.x * 256 + threadIdx.x;     // 49152
    int l = gid >> 14;
    int rem = gid & 16383;
    int k = rem >> 7, n = rem & 127;
    Wt[l * 16384 + n * 128 + k] = f2bf(Ws[gid]);
  } else {
    int gid = (blockIdx.x - 192) * 256 + threadIdx.x;   // 8192
    int i = gid >> 6, j = gid & 63;                     // i = k, j = out col
    float acc = 0.f;
    for (int k = 0; k < 128; ++k) acc += Wp1[i * 128 + k] * Wp2[k * 64 + j];
    Wct[j * 128 + i] = f2bf(acc);
    if (gid < 64) {
      float b = bp2[gid];
      for (int k = 0; k < 128; ++k) b += bp1[k] * Wp2[k * 64 + gid];
      bc[gid] = b;
    }
  }
}

// ---------------- MFMA GEMM + fused attention scores ----------------
// H(bf16)[M x 128] = bf16(A) @ W + bias ; sdst/ssrc from f32 accumulators.
// SWAPPED mfma(fb, fa): thread holds H[row = tile+li][cols g*4+{0..3}] ->
// vectorized ushort4 H stores, float4 bias/att loads, 2-shfl score reduce.

template <bool F32A>
__global__ __launch_bounds__(256) void k_gemm_mfma(const void* __restrict__ Aptr,
                                                   const unsigned short* __restrict__ Bt,
                                                   const float* __restrict__ bias,
                                                   const float* __restrict__ att,
                                                   unsigned short* __restrict__ H,
                                                   float* __restrict__ sdst,
                                                   float* __restrict__ ssrc, int M) {
  __shared__ float spi[2][128];
  __shared__ float spj[2][128];
  int tid = threadIdx.x;
  int w = tid >> 6, l = tid & 63;
  int g = l >> 4, li = l & 15;
  int row0 = blockIdx.x * 128;
  int mw = (w >> 1) * 64, nw = (w & 1) * 64;

  floatx4 acc[4][4] = {};   // [ti = row tile][tj = col tile]

  for (int ks = 0; ks < 4; ++ks) {
    short8 fa[4], fb[4];
#pragma unroll
    for (int t = 0; t < 4; ++t) {
      int row = row0 + mw + t * 16 + li;
      row = row < M ? row : M - 1;
      if (F32A) {
        const float* ap = (const float*)Aptr + (size_t)row * 128 + ks * 32 + g * 8;
        float4 v0 = *(const float4*)ap;
        float4 v1 = *(const float4*)(ap + 4);
        short8 f;
        f[0] = (short)f2bf(v0.x); f[1] = (short)f2bf(v0.y);
        f[2] = (short)f2bf(v0.z); f[3] = (short)f2bf(v0.w);
        f[4] = (short)f2bf(v1.x); f[5] = (short)f2bf(v1.y);
        f[6] = (short)f2bf(v1.z); f[7] = (short)f2bf(v1.w);
        fa[t] = f;
      } else {
        fa[t] = *(const short8*)((const unsigned short*)Aptr +
                                 (size_t)row * 128 + ks * 32 + g * 8);
      }
      fb[t] = *(const short8*)(Bt + (nw + t * 16 + li) * 128 + ks * 32 + g * 8);
    }
#pragma unroll
    for (int ti = 0; ti < 4; ++ti)
#pragma unroll
      for (int tj = 0; tj < 4; ++tj)
        acc[ti][tj] = __builtin_amdgcn_mfma_f32_16x16x32_bf16(fb[tj], fa[ti],
                                                              acc[ti][tj], 0, 0, 0);
  }

  float pis[4] = {0.f, 0.f, 0.f, 0.f};
  float pjs[4] = {0.f, 0.f, 0.f, 0.f};
#pragma unroll
  for (int tj = 0; tj < 4; ++tj) {
    int c0 = nw + tj * 16 + g * 4;
    float4 bb = *(const float4*)&bias[c0];
    float4 ai = *(const float4*)&att[c0];
    float4 aj = *(const float4*)&att[128 + c0];
#pragma unroll
    for (int ti = 0; ti < 4; ++ti) {
      int row = row0 + mw + ti * 16 + li;
      float v0 = acc[ti][tj][0] + bb.x;
      float v1 = acc[ti][tj][1] + bb.y;
      float v2 = acc[ti][tj][2] + bb.z;
      float v3 = acc[ti][tj][3] + bb.w;
      if (row < M) {
        ushort4 p;
        p.x = f2bf(v0); p.y = f2bf(v1); p.z = f2bf(v2); p.w = f2bf(v3);
        *(ushort4*)&H[(size_t)row * 128 + c0] = p;
      }
      pis[ti] += v0 * ai.x + v1 * ai.y + v2 * ai.z + v3 * ai.w;
      pjs[ti] += v0 * aj.x + v1 * aj.y + v2 * aj.z + v3 * aj.w;
    }
  }
#pragma unroll
  for (int ti = 0; ti < 4; ++ti) {
    float a = pis[ti], b = pjs[ti];
    a += __shfl_xor(a, 16); a += __shfl_xor(a, 32);
    b += __shfl_xor(b, 16); b += __shfl_xor(b, 32);
    if (g == 0) {
      spi[w & 1][mw + ti * 16 + li] = a;
      spj[w & 1][mw + ti * 16 + li] = b;
    }
  }
  __syncthreads();
  if (tid < 128) {
    int row = row0 + tid;
    if (row < M) {
      sdst[row] = spi[0][tid] + spi[1][tid];
      ssrc[row] = spj[0][tid] + spj[1][tid];
    }
  }
}

// ---------------- softmax + aggregation: 4 nodes per wave (16 lanes each) ----------------
// offs holds END offsets (start of node n = offs[n-1], or 0). Output bf16.

__global__ __launch_bounds__(256) void k_gather(const unsigned short* __restrict__ H,
                                                const float* __restrict__ sdst,
                                                const float* __restrict__ ssrc,
                                                const int* __restrict__ csr,
                                                const int* __restrict__ offs,
                                                const float* __restrict__ bias,
                                                unsigned short* __restrict__ xout, int N) {
  int tid = threadIdx.x;
  int lane = tid & 63;
  int grp = tid >> 4;            // 16 node-groups per block
  int l16 = tid & 15;
  int gbase = lane & 48;         // group's base lane within the wave
  int n = blockIdx.x * 16 + grp;
  bool valid = (n < N);
  int end = valid ? offs[n] : 0;
  int start = (valid && n > 0) ? offs[n - 1] : 0;
  float sdn = valid ? sdst[n] : 0.f;

  float m = -INFINITY, ssum = 0.f;
  float acc[8] = {};

  for (int base = start; base < end; base += 16) {
    int k = base + l16;
    int s = 0;
    float sc = -INFINITY;
    if (k < end) {
      s = csr[k];
      float e = sdn + ssrc[s];
      sc = e > 0.f ? e : 0.2f * e;
    }
    float cm = sc;
#pragma unroll
    for (int off = 8; off; off >>= 1) cm = fmaxf(cm, __shfl_xor(cm, off));
    float nm = fmaxf(m, cm);
    float scale = __expf(m - nm);      // first chunk: exp(-inf)=0, acc/ssum are 0
#pragma unroll
    for (int i = 0; i < 8; ++i) acc[i] *= scale;
    float wgt = (k < end) ? __expf(sc - nm) : 0.f;
    float cs = wgt;
#pragma unroll
    for (int off = 8; off; off >>= 1) cs += __shfl_xor(cs, off);
    ssum = ssum * scale + cs;
    m = nm;
    int cc = end - base; if (cc > 16) cc = 16;
    for (int j = 0; j < cc; ++j) {
      float wj = __shfl(wgt, gbase + j);
      int sj = __shfl(s, gbase + j);
      short8 hv = *(const short8*)(H + (size_t)sj * 128 + l16 * 8);
#pragma unroll
      for (int i = 0; i < 8; ++i)
        acc[i] += wj * bf2f((unsigned short)hv[i]);
    }
  }

  if (valid) {
    float inv = 1.0f / (ssum + 1e-16f);
    float4 b0 = *(const float4*)&bias[l16 * 8];
    float4 b1 = *(const float4*)&bias[l16 * 8 + 4];
    float bb[8] = {b0.x, b0.y, b0.z, b0.w, b1.x, b1.y, b1.z, b1.w};
    short8 o;
#pragma unroll
    for (int i = 0; i < 8; ++i)
      o[i] = (short)f2bf(fmaxf(acc[i] * inv + bb[i], 0.f));
    *(short8*)(xout + (size_t)n * 128 + l16 * 8) = o;
  }
}

// ---------------- head: out = log_softmax(xb @ Wc + bc), swapped MFMA ----------------
// thread holds out[row][tj*16 + g*4 + {0..3}] -> float4 stores, 2-shfl reductions.

__global__ __launch_bounds__(256) void k_head_mfma(const unsigned short* __restrict__ Xb,
                                                   const unsigned short* __restrict__ Wct,
                                                   const float* __restrict__ bc,
                                                   float* __restrict__ out, int M) {
  int tid = threadIdx.x;
  int w = tid >> 6, l = tid & 63;
  int g = l >> 4, li = l & 15;
  int row0 = blockIdx.x * 128;
  int mw = w * 32;

  floatx4 acc[2][4] = {};

  for (int ks = 0; ks < 4; ++ks) {
    short8 fa[2], fb[4];
#pragma unroll
    for (int t = 0; t < 2; ++t) {
      int row = row0 + mw + t * 16 + li;
      row = row < M ? row : M - 1;
      fa[t] = *(const short8*)(Xb + (size_t)row * 128 + ks * 32 + g * 8);
    }
#pragma unroll
    for (int t = 0; t < 4; ++t)
      fb[t] = *(const short8*)(Wct + (t * 16 + li) * 128 + ks * 32 + g * 8);
#pragma unroll
    for (int ti = 0; ti < 2; ++ti)
#pragma unroll
      for (int tj = 0; tj < 4; ++tj)
        acc[ti][tj] = __builtin_amdgcn_mfma_f32_16x16x32_bf16(fb[tj], fa[ti],
                                                              acc[ti][tj], 0, 0, 0);
  }

#pragma unroll
  for (int ti = 0; ti < 2; ++ti) {
    float v[16];
    float mx = -INFINITY;
#pragma unroll
    for (int tj = 0; tj < 4; ++tj) {
      int c0 = tj * 16 + g * 4;
      float4 bb = *(const float4*)&bc[c0];
      v[tj * 4 + 0] = acc[ti][tj][0] + bb.x;
      v[tj * 4 + 1] = acc[ti][tj][1] + bb.y;
      v[tj * 4 + 2] = acc[ti][tj][2] + bb.z;
      v[tj * 4 + 3] = acc[ti][tj][3] + bb.w;
#pragma unroll
      for (int q = 0; q < 4; ++q) mx = fmaxf(mx, v[tj * 4 + q]);
    }
    mx = fmaxf(mx, __shfl_xor(mx, 16));
    mx = fmaxf(mx, __shfl_xor(mx, 32));
    float s = 0.f;
#pragma unroll
    for (int q = 0; q < 16; ++q) s += __expf(v[q] - mx);
    s += __shfl_xor(s, 16);
    s += __shfl_xor(s, 32);
    float ls = mx + __logf(s);
    int row = row0 + mw + ti * 16 + li;
    if (row < M) {
#pragma unroll
      for (int tj = 0; tj < 4; ++tj) {
        float4 o = make_float4(v[tj * 4 + 0] - ls, v[tj * 4 + 1] - ls,
                               v[tj * 4 + 2] - ls, v[tj * 4 + 3] - ls);
        *(float4*)&out[(size_t)row * 64 + tj * 16 + g * 4] = o;
      }
    }
  }
}

// ---------------- launch ----------------

extern "C" void kernel_launch(void* const* d_in, const int* in_sizes, int n_in,
                              void* d_out, int out_size, void* d_ws, size_t ws_size,
                              hipStream_t stream) {
  const float* x      = (const float*)d_in[0];
  const int*   ei     = (const int*)d_in[1];
  const float* Ws     = (const float*)d_in[2];
  const float* bs     = (const float*)d_in[3];
  const float* atts   = (const float*)d_in[4];
  const float* biases = (const float*)d_in[5];
  const float* Wp1    = (const float*)d_in[6];
  const float* bp1    = (const float*)d_in[7];
  const float* Wp2    = (const float*)d_in[8];
  const float* bp2    = (const float*)d_in[9];
  float* out = (float*)d_out;

  int N = in_sizes[0] / 128;
  int E = in_sizes[1] / 2;
  int Np = (N + 3) & ~3;
  int nb = (N + 1023) / 1024;

  float* sdst = (float*)d_ws;
  float* ssrc = sdst + Np;
  float* bc   = ssrc + Np;
  unsigned short* xbuf = (unsigned short*)(bc + 64);   // bf16 gather output
  unsigned short* H    = xbuf + (size_t)Np * 128;      // bf16 h
  unsigned short* Wt   = H + (size_t)Np * 128;         // 3 x [n][k]
  unsigned short* Wct  = Wt + 3 * 16384;               // [64][128]
  int* deg    = (int*)(Wct + 8192);
  int* offs   = deg + Np;
  int* partial  = offs + Np;
  int* partialx = partial + 1024;
  int* csr      = partialx + 1028;

  // weight prep (transpose + head fold), independent of CSR
  k_prepfold<<<224, 256, 0, stream>>>(Ws, Wp1, bp1, Wp2, bp2, Wt, Wct, bc);

  // CSR by dst
  hipMemsetAsync(deg, 0, (size_t)N * sizeof(int), stream);
  k_hist<<<(E + 255) / 256, 256, 0, stream>>>(ei, deg, E);
  k_scan1<<<nb, 1024, 0, stream>>>(deg, offs, partial, N);
  k_scan<<<1, 1024, 0, stream>>>(partial, partialx, nb);
  k_add<<<nb, 1024, 0, stream>>>(offs, partialx, N);
  k_fill<<<(E + 255) / 256, 256, 0, stream>>>(ei, offs, csr, E);   // offs -> ends

  for (int l = 0; l < 3; ++l) {
    if (l == 0)
      k_gemm_mfma<true><<<(N + 127) / 128, 256, 0, stream>>>(
          x, Wt, bs, atts, H, sdst, ssrc, N);
    else
      k_gemm_mfma<false><<<(N + 127) / 128, 256, 0, stream>>>(
          xbuf, Wt + (size_t)l * 16384, bs + (size_t)l * 128,
          atts + (size_t)l * 256, H, sdst, ssrc, N);
    k_gather<<<(N + 15) / 16, 256, 0, stream>>>(H, sdst, ssrc, csr, offs,
                                                biases + (size_t)l * 128, xbuf, N);
  }

  k_head_mfma<<<(N + 127) / 128, 256, 0, stream>>>(xbuf, Wct, bc, out, N);
}